// Round 6
// baseline (756.226 us; speedup 1.0000x reference)
//
#include <hip/hip_runtime.h>
#include <hip/hip_bf16.h>
#include <stdint.h>

typedef __bf16 bf16;
typedef __bf16 bf16x8 __attribute__((ext_vector_type(8)));
typedef float f32x4 __attribute__((ext_vector_type(4)));

#define MFMA16(a, b, c) __builtin_amdgcn_mfma_f32_16x16x32_bf16((a), (b), (c), 0, 0, 0)

// async global->LDS, 16B per lane; lane-consecutive chunk pointers (lane0 = base).
__device__ __forceinline__ void g2lds16(const void* g, void* l) {
  __builtin_amdgcn_global_load_lds((__attribute__((address_space(1))) void*)g,
                                   (__attribute__((address_space(3))) void*)l,
                                   16, 0, 0);
}

// fp32 -> bf16 converters (8 elems/thread, 16B stores)
__global__ __launch_bounds__(256) void cvt3(const float* __restrict__ a,
                                            const float* __restrict__ b,
                                            const float* __restrict__ c,
                                            bf16* x, bf16* y, bf16* z_) {
  int zi = blockIdx.y;
  const float* s = (zi == 0) ? a : (zi == 1) ? b : c;
  bf16* d = (zi == 0) ? x : (zi == 1) ? y : z_;
  size_t i = ((size_t)blockIdx.x * 256 + threadIdx.x) * 8;
  float4 f0 = *(const float4*)(s + i);
  float4 f1 = *(const float4*)(s + i + 4);
  union { bf16 h[8]; uint4 u; } t;
  t.h[0] = (bf16)f0.x; t.h[1] = (bf16)f0.y; t.h[2] = (bf16)f0.z; t.h[3] = (bf16)f0.w;
  t.h[4] = (bf16)f1.x; t.h[5] = (bf16)f1.y; t.h[6] = (bf16)f1.z; t.h[7] = (bf16)f1.w;
  *(uint4*)(d + i) = t.u;
}
__global__ __launch_bounds__(256) void cvt4(const float* __restrict__ a,
                                            const float* __restrict__ b,
                                            const float* __restrict__ c,
                                            const float* __restrict__ e,
                                            bf16* x, bf16* y, bf16* z_, bf16* w) {
  int zi = blockIdx.y;
  const float* s = (zi == 0) ? a : (zi == 1) ? b : (zi == 2) ? c : e;
  bf16* d = (zi == 0) ? x : (zi == 1) ? y : (zi == 2) ? z_ : w;
  size_t i = ((size_t)blockIdx.x * 256 + threadIdx.x) * 8;
  float4 f0 = *(const float4*)(s + i);
  float4 f1 = *(const float4*)(s + i + 4);
  union { bf16 h[8]; uint4 u; } t;
  t.h[0] = (bf16)f0.x; t.h[1] = (bf16)f0.y; t.h[2] = (bf16)f0.z; t.h[3] = (bf16)f0.w;
  t.h[4] = (bf16)f1.x; t.h[5] = (bf16)f1.y; t.h[6] = (bf16)f1.z; t.h[7] = (bf16)f1.w;
  *(uint4*)(d + i) = t.u;
}

// ---------------------------------------------------------------------------
// 128x128 GEMM-NT core (bf16 LDS tiles, XOR-swizzled 16B chunks): m97 pattern.
// ---------------------------------------------------------------------------
__device__ __forceinline__ void gemm_core_128(const bf16* __restrict__ A,
                                              const bf16* __restrict__ W,
                                              int m0, int n0, int tid,
                                              uint4* sA, uint4* sB,
                                              f32x4 acc[4][4]) {
  const int lane = tid & 63, quad = lane >> 4, l16 = lane & 15;
  const int wave = tid >> 6;
  const int wm = (wave >> 1) * 64, wn = (wave & 1) * 64;
#pragma unroll
  for (int i = 0; i < 4; i++)
#pragma unroll
    for (int j = 0; j < 4; j++) {
      f32x4 z = {0.f, 0.f, 0.f, 0.f};
      acc[i][j] = z;
    }
  for (int kk = 0; kk < 16; kk++) {
    const int k0 = kk * 64;
    __syncthreads();
#pragma unroll
    for (int t = 0; t < 4; t++) {
      int c = t * 256 + tid;
      int r = c >> 3, jb = (c & 7) ^ (r & 7);
      g2lds16(A + (size_t)(m0 + r) * 1024 + k0 + jb * 8, sA + c);
    }
#pragma unroll
    for (int t = 0; t < 4; t++) {
      int c = t * 256 + tid;
      int r = c >> 3, jb = (c & 7) ^ (r & 7);
      g2lds16(W + (size_t)(n0 + r) * 1024 + k0 + jb * 8, sB + c);
    }
    __syncthreads();
#pragma unroll
    for (int kc = 0; kc < 2; kc++) {
      bf16x8 af[4], bfr[4];
#pragma unroll
      for (int i = 0; i < 4; i++) {
        int row = wm + i * 16 + l16;
        af[i] = *(const bf16x8*)(sA + row * 8 + (((kc << 2) + quad) ^ (row & 7)));
      }
#pragma unroll
      for (int j = 0; j < 4; j++) {
        int row = wn + j * 16 + l16;
        bfr[j] = *(const bf16x8*)(sB + row * 8 + (((kc << 2) + quad) ^ (row & 7)));
      }
#pragma unroll
      for (int i = 0; i < 4; i++)
#pragma unroll
        for (int j = 0; j < 4; j++)
          acc[i][j] = MFMA16(af[i], bfr[j], acc[i][j]);
    }
  }
}

// C/D layout: row(m) = quad*4 + reg, col(n) = lane&15 (m89/m91 verified).

// QKV projection (bf16 temps in, bf16 internal out; fp32 bias).
__global__ __launch_bounds__(256, 3) void qkv_gemm(
    const bf16* __restrict__ qin, const bf16* __restrict__ kin,
    const bf16* __restrict__ vin, const bf16* __restrict__ Wq,
    const bf16* __restrict__ Wk, const bf16* __restrict__ Wv,
    const float* __restrict__ bq, const float* __restrict__ bk,
    const float* __restrict__ bv, bf16* __restrict__ qw, bf16* __restrict__ kw,
    bf16* __restrict__ vTw) {
  __shared__ uint4 sA[1024], sB[1024];
  const int z = blockIdx.z;
  const bf16* A = (z == 0) ? qin : (z == 1) ? kin : vin;
  const bf16* W = (z == 0) ? Wq : (z == 1) ? Wk : Wv;
  const float* bias = (z == 0) ? bq : (z == 1) ? bk : bv;
  const int m0 = blockIdx.x * 128, n0 = blockIdx.y * 128;
  const int tid = threadIdx.x;
  f32x4 acc[4][4];
  gemm_core_128(A, W, m0, n0, tid, sA, sB, acc);
  const int lane = tid & 63, quad = lane >> 4, l16 = lane & 15;
  const int wave = tid >> 6;
  const int wm = (wave >> 1) * 64, wn = (wave & 1) * 64;
  if (z < 2) {
    bf16* out = (z == 0) ? qw : kw;
#pragma unroll
    for (int j = 0; j < 4; j++) {
      int n = n0 + wn + j * 16 + l16;
      float bvv = bias[n];
      int h = n >> 6, dk = n & 63;
#pragma unroll
      for (int i = 0; i < 4; i++) {
        int mbase = m0 + wm + i * 16 + quad * 4;
#pragma unroll
        for (int r = 0; r < 4; r++) {
          int m = mbase + r;
          int b = m >> 11, s = m & 2047;
          out[(((size_t)(b * 16 + h) * 2048 + s) << 6) + dk] =
              (bf16)(acc[i][j][r] + bvv);
        }
      }
    }
  } else {
#pragma unroll
    for (int j = 0; j < 4; j++) {
      int n = n0 + wn + j * 16 + l16;
      float bvv = bias[n];
      int h = n >> 6, dk = n & 63;
#pragma unroll
      for (int i = 0; i < 4; i++) {
        int m = m0 + wm + i * 16 + quad * 4;
        int b = m >> 11, s = m & 2047;
        union { bf16 hh[4]; uint2 u; } tmp;
#pragma unroll
        for (int r = 0; r < 4; r++) tmp.hh[r] = (bf16)(acc[i][j][r] + bvv);
        *(uint2*)&vTw[((size_t)((b * 16 + h) * 64 + dk) << 11) + s] = tmp.u;
      }
    }
  }
}

// Output projection: fp32 store + fp32 bias.
__global__ __launch_bounds__(256, 3) void out_gemm(const bf16* __restrict__ X,
                                                   const bf16* __restrict__ Wo,
                                                   const float* __restrict__ bo,
                                                   float* __restrict__ out) {
  __shared__ uint4 sA[1024], sB[1024];
  const int m0 = blockIdx.x * 128, n0 = blockIdx.y * 128;
  const int tid = threadIdx.x;
  f32x4 acc[4][4];
  gemm_core_128(X, Wo, m0, n0, tid, sA, sB, acc);
  const int lane = tid & 63, quad = lane >> 4, l16 = lane & 15;
  const int wave = tid >> 6;
  const int wm = (wave >> 1) * 64, wn = (wave & 1) * 64;
#pragma unroll
  for (int j = 0; j < 4; j++) {
    int n = n0 + wn + j * 16 + l16;
    float bvv = bo[n];
#pragma unroll
    for (int i = 0; i < 4; i++) {
      int mbase = m0 + wm + i * 16 + quad * 4;
#pragma unroll
      for (int r = 0; r < 4; r++) {
        int m = mbase + r;
        out[((size_t)m << 10) + n] = acc[i][j][r] + bvv;
      }
    }
  }
}

// ---------------------------------------------------------------------------
// Attention v6: QBLK=128, KVBLK=128 (r4 sync template, bigger Q-tile).
//  - 4 waves x 32 q-rows (2 sub-tiles of 16); barriers per q-row HALVED vs r4
//    (r5 measured the inverse: 2x barrier density cost +21 us).
//  - LDS 80 KiB: sK dbuf 2x16K | sV 16K | sP 32K (sQ aliases sP); 2 blocks/CU;
//    grid 512 = exactly one resident round (zero tail).
//  - Same proven swizzles/prefetch/fixed-shift softmax/NT stores as r4.
// ---------------------------------------------------------------------------
__global__ __launch_bounds__(256, 2) void attn_kernel(
    const bf16* __restrict__ qw, const bf16* __restrict__ kw,
    const bf16* __restrict__ vT, const int* __restrict__ mask,
    float* __restrict__ attnF, bf16* __restrict__ xw) {
  __shared__ uint4 smem[5120];      // 80 KiB
  uint4* const sK0 = smem;          // 16K: 128 k-rows x 64 d
  uint4* const sK1 = smem + 1024;   // 16K
  uint4* const sV = smem + 2048;    // 16K: 64 dk-rows x 128 k
  uint4* const sP = smem + 3072;    // 32K: 128 q-rows x 128 k (bf16)
  uint4* const sQ = smem + 3072;    // alias: Q consumed before first sP write

  const int tid = threadIdx.x, wave = tid >> 6, lane = tid & 63;
  const int quad = lane >> 4, l16 = lane & 15;
  // bijective XCD swizzle (nwg=512 % 8 == 0): XCD k gets bh in [4k, 4k+4)
  const int wgid = blockIdx.y * 16 + blockIdx.x;
  const int swz = (wgid & 7) * 64 + (wgid >> 3);
  const int qt = swz & 15, bh = swz >> 4, b = bh >> 4, h = bh & 15;
  const int q0 = qt * 128;
  const bf16* qbase = qw + (size_t)bh * (2048 * 64);
  const bf16* kbase = kw + (size_t)bh * (2048 * 64);
  const bf16* vbase = vT + (size_t)bh * (64 * 2048);
  const int* mrow = mask + b * 2048;

  const float SC = 0.125f * 1.44269504f;  // log2(e)/8

  auto stageK = [&](uint4* buf, int kt) {
#pragma unroll
    for (int t = 0; t < 4; t++) {
      int c = t * 256 + tid;
      int r = c >> 3, jb = (c & 7) ^ (r & 7);
      g2lds16(kbase + (size_t)(kt * 128 + r) * 64 + jb * 8, buf + c);
    }
  };
  auto stageV = [&](int kt) {
#pragma unroll
    for (int t = 0; t < 4; t++) {
      int c = t * 256 + tid;
      int rv = c >> 4, jb = (c & 15) ^ (rv & 15);
      g2lds16(vbase + (size_t)rv * 2048 + kt * 128 + jb * 8, sV + c);
    }
  };

  // stage Q (16 KiB, into sP region) + K tile 0; one drain for both
#pragma unroll
  for (int t = 0; t < 4; t++) {
    int c = t * 256 + tid;
    int r = c >> 3, jb = (c & 7) ^ (r & 7);
    g2lds16(qbase + (size_t)(q0 + r) * 64 + jb * 8, sQ + c);
  }
  stageK(sK0, 0);
  __syncthreads();

  bf16x8 aq[2][2];  // [sub-tile][kc]
#pragma unroll
  for (int st = 0; st < 2; st++) {
    int row = wave * 32 + st * 16 + l16;
    aq[st][0] = *(const bf16x8*)(sQ + row * 8 + ((quad) ^ (row & 7)));
    aq[st][1] = *(const bf16x8*)(sQ + row * 8 + ((4 + quad) ^ (row & 7)));
  }
  float lpart[2][4];
#pragma unroll
  for (int st = 0; st < 2; st++)
#pragma unroll
    for (int r = 0; r < 4; r++) lpart[st][r] = 0.f;

  // -------- Pass A: per-lane exp2 partial sums; 1 barrier/kt ----------------
  for (int kt = 0; kt < 16; kt++) {
    uint4* kcur = (kt & 1) ? sK1 : sK0;
    if (kt < 15) {
      stageK((kt & 1) ? sK0 : sK1, kt + 1);  // prefetch next K
    } else {
      stageK(sK0, 0);  // pre-stage pass B's first tiles
      stageV(0);
    }
#pragma unroll
    for (int st = 0; st < 2; st++) {
      f32x4 sc[8];
#pragma unroll
      for (int ns = 0; ns < 8; ns++) {
        f32x4 z = {0.f, 0.f, 0.f, 0.f};
        sc[ns] = z;
      }
#pragma unroll
      for (int kc = 0; kc < 2; kc++)
#pragma unroll
        for (int ns = 0; ns < 8; ns++) {
          int row = ns * 16 + l16;
          bf16x8 bk = *(const bf16x8*)(kcur + row * 8 +
                                       (((kc << 2) + quad) ^ (row & 7)));
          sc[ns] = MFMA16(aq[st][kc], bk, sc[ns]);
        }
#pragma unroll
      for (int ns = 0; ns < 8; ns++) {
        float madd = (mrow[kt * 128 + ns * 16 + l16] == 0) ? -1.0e9f : 0.0f;
#pragma unroll
        for (int r = 0; r < 4; r++)
          lpart[st][r] += exp2f(sc[ns][r] * SC + madd);
      }
    }
    __syncthreads();  // protects kcur for overwrite; drains prefetch
  }

  float invl[2][4];
  size_t arow[2][4];
#pragma unroll
  for (int st = 0; st < 2; st++)
#pragma unroll
    for (int r = 0; r < 4; r++) {
      float v = lpart[st][r];
#pragma unroll
      for (int off = 8; off >= 1; off >>= 1) v += __shfl_xor(v, off, 16);
      invl[st][r] = 1.f / fmaxf(v, 1.0e-30f);
      arow[st][r] =
          (size_t)(bh * 2048 + q0 + wave * 32 + st * 16 + quad * 4 + r) * 2048;
    }
  f32x4 xacc[2][4];
#pragma unroll
  for (int st = 0; st < 2; st++)
#pragma unroll
    for (int nd = 0; nd < 4; nd++) {
      f32x4 z = {0.f, 0.f, 0.f, 0.f};
      xacc[st][nd] = z;
    }
  bf16* sPb = (bf16*)sP;

  // -------- Pass B: recompute scores, store exact attn, PV ------------------
  for (int kt = 0; kt < 16; kt++) {
    uint4* kcur = (kt & 1) ? sK1 : sK0;
    if (kt < 15) stageK((kt & 1) ? sK0 : sK1, kt + 1);  // prefetch next K
    f32x4 sc[2][8];
#pragma unroll
    for (int st = 0; st < 2; st++)
#pragma unroll
      for (int ns = 0; ns < 8; ns++) {
        f32x4 z = {0.f, 0.f, 0.f, 0.f};
        sc[st][ns] = z;
      }
#pragma unroll
    for (int st = 0; st < 2; st++)
#pragma unroll
      for (int kc = 0; kc < 2; kc++)
#pragma unroll
        for (int ns = 0; ns < 8; ns++) {
          int row = ns * 16 + l16;
          bf16x8 bk = *(const bf16x8*)(kcur + row * 8 +
                                       (((kc << 2) + quad) ^ (row & 7)));
          sc[st][ns] = MFMA16(aq[st][kc], bk, sc[st][ns]);
        }
#pragma unroll
    for (int st = 0; st < 2; st++)
#pragma unroll
      for (int ns = 0; ns < 8; ns++) {
        float madd = (mrow[kt * 128 + ns * 16 + l16] == 0) ? -1.0e9f : 0.0f;
        int col = ns * 16 + l16;
#pragma unroll
        for (int r = 0; r < 4; r++) {
          float p = exp2f(sc[st][ns][r] * SC + madd) * invl[st][r];
          sc[st][ns][r] = p;
          int qrow = wave * 32 + st * 16 + quad * 4 + r;
          int chunk = qrow * 16 + ((col >> 3) ^ (qrow & 15));
          sPb[chunk * 8 + (col & 7)] = (bf16)p;
        }
      }
    __syncthreads();  // B1: sP visible; V(kt) + K(kt+1) drained
    // PV: A = own wave's 32 q-rows of P, B = V^T tile
#pragma unroll
    for (int st = 0; st < 2; st++)
#pragma unroll
      for (int kc2 = 0; kc2 < 4; kc2++) {
        int rowp = wave * 32 + st * 16 + l16;
        bf16x8 ap = *(const bf16x8*)(sP + rowp * 16 +
                                     (((kc2 << 2) + quad) ^ (rowp & 15)));
#pragma unroll
        for (int nd = 0; nd < 4; nd++) {
          int rv = nd * 16 + l16;
          bf16x8 bv = *(const bf16x8*)(sV + rv * 16 +
                                       (((kc2 << 2) + quad) ^ (rv & 15)));
          xacc[st][nd] = MFMA16(ap, bv, xacc[st][nd]);
        }
      }
    __syncthreads();  // B2: all waves done reading sV/sP
    if (kt < 15) stageV(kt + 1);  // overlaps next QK^T+softmax, drains at B1
    // attn stores from registers; nontemporal (bypass L2), drain at next B1
#pragma unroll
    for (int st = 0; st < 2; st++)
#pragma unroll
      for (int ns = 0; ns < 8; ns++) {
        int col = kt * 128 + ns * 16 + l16;
#pragma unroll
        for (int r = 0; r < 4; r++)
          __builtin_nontemporal_store(sc[st][ns][r], &attnF[arow[st][r] + col]);
      }
  }
#pragma unroll
  for (int st = 0; st < 2; st++)
#pragma unroll
    for (int nd = 0; nd < 4; nd++) {
      int dk = nd * 16 + l16;
#pragma unroll
      for (int r = 0; r < 4; r++) {
        int qrow = q0 + wave * 32 + st * 16 + quad * 4 + r;
        xw[((size_t)(b * 2048 + qrow) << 10) + h * 64 + dk] =
            (bf16)xacc[st][nd][r];
      }
    }
}

extern "C" void kernel_launch(void* const* d_in, const int* in_sizes, int n_in,
                              void* d_out, int out_size, void* d_ws,
                              size_t ws_size, hipStream_t stream) {
  const float* query = (const float*)d_in[0];
  const float* key = (const float*)d_in[1];
  const float* value = (const float*)d_in[2];
  const int* mask = (const int*)d_in[3];
  const float* Wq = (const float*)d_in[4];
  const float* bq = (const float*)d_in[5];
  const float* Wk = (const float*)d_in[6];
  const float* bk = (const float*)d_in[7];
  const float* Wv = (const float*)d_in[8];
  const float* bv = (const float*)d_in[9];
  const float* Wo = (const float*)d_in[10];
  const float* bo = (const float*)d_in[11];

  float* outF = (float*)d_out;           // [4096][1024] fp32
  float* attnF = outF + (size_t)4194304; // [32][2048][2048] fp32

  // bf16 temps carved from the (not-yet-written) attn region of d_out:
  bf16* tQ = (bf16*)attnF;               // 4Mi elems
  bf16* tK = tQ + (size_t)4194304;
  bf16* tV = tK + (size_t)4194304;
  bf16* tWq = tV + (size_t)4194304;      // 1Mi elems each
  bf16* tWk = tWq + (size_t)1048576;
  bf16* tWv = tWk + (size_t)1048576;     // 30 MiB total << 537 MB region

  bf16* qw = (bf16*)d_ws;                // internal bf16 q  8 MiB
  bf16* kw = qw + (size_t)4194304;       // 8 MiB
  bf16* vT = kw + (size_t)4194304;       // 8 MiB
  bf16* xw = vT + (size_t)4194304;       // 8 MiB
  bf16* WoB = xw + (size_t)4194304;      // 2 MiB (must outlive attn_kernel)

  cvt3<<<dim3(2048, 3), 256, 0, stream>>>(query, key, value, tQ, tK, tV);
  cvt4<<<dim3(512, 4), 256, 0, stream>>>(Wq, Wk, Wv, Wo, tWq, tWk, tWv, WoB);
  qkv_gemm<<<dim3(32, 8, 3), 256, 0, stream>>>(tQ, tK, tV, tWq, tWk, tWv, bq,
                                               bk, bv, qw, kw, vT);
  attn_kernel<<<dim3(16, 32), 256, 0, stream>>>(qw, kw, vT, mask, attnF, xw);
  out_gemm<<<dim3(32, 8), 256, 0, stream>>>(xw, WoB, bo, outF);
}

// Round 7
// 718.052 us; speedup vs baseline: 1.0532x; 1.0532x over previous
//
#include <hip/hip_runtime.h>
#include <hip/hip_bf16.h>
#include <stdint.h>

typedef __bf16 bf16;
typedef __bf16 bf16x8 __attribute__((ext_vector_type(8)));
typedef float f32x4 __attribute__((ext_vector_type(4)));

#define MFMA16(a, b, c) __builtin_amdgcn_mfma_f32_16x16x32_bf16((a), (b), (c), 0, 0, 0)

// async global->LDS, 16B per lane; lane-consecutive chunk pointers (lane0 = base).
__device__ __forceinline__ void g2lds16(const void* g, void* l) {
  __builtin_amdgcn_global_load_lds((__attribute__((address_space(1))) void*)g,
                                   (__attribute__((address_space(3))) void*)l,
                                   16, 0, 0);
}

// Fused fp32 -> bf16 converter for all 7 tensors (range-dispatched 1D grid).
// blocks [0,6144): Q,K,V (2048 each); [6144,8192): Wq,Wk,Wv,Wo (512 each).
__global__ __launch_bounds__(256) void cvt_all(
    const float* __restrict__ q, const float* __restrict__ k,
    const float* __restrict__ v, const float* __restrict__ wq,
    const float* __restrict__ wk, const float* __restrict__ wv,
    const float* __restrict__ wo, bf16* tq, bf16* tk, bf16* tv, bf16* twq,
    bf16* twk, bf16* twv, bf16* two) {
  int bid = blockIdx.x;
  const float* s;
  bf16* d;
  size_t off;
  if (bid < 6144) {
    int z = bid >> 11, lb = bid & 2047;
    s = (z == 0) ? q : (z == 1) ? k : v;
    d = (z == 0) ? tq : (z == 1) ? tk : tv;
    off = (size_t)lb * 2048;
  } else {
    int t = bid - 6144;
    int z = t >> 9, lb = t & 511;
    s = (z == 0) ? wq : (z == 1) ? wk : (z == 2) ? wv : wo;
    d = (z == 0) ? twq : (z == 1) ? twk : (z == 2) ? twv : two;
    off = (size_t)lb * 2048;
  }
  size_t i = off + (size_t)threadIdx.x * 8;
  float4 f0 = *(const float4*)(s + i);
  float4 f1 = *(const float4*)(s + i + 4);
  union { bf16 h[8]; uint4 u; } t;
  t.h[0] = (bf16)f0.x; t.h[1] = (bf16)f0.y; t.h[2] = (bf16)f0.z; t.h[3] = (bf16)f0.w;
  t.h[4] = (bf16)f1.x; t.h[5] = (bf16)f1.y; t.h[6] = (bf16)f1.z; t.h[7] = (bf16)f1.w;
  *(uint4*)(d + i) = t.u;
}

// ---------------------------------------------------------------------------
// 128x128 GEMM-NT core (bf16 LDS tiles, XOR-swizzled 16B chunks): m97 pattern.
// ---------------------------------------------------------------------------
__device__ __forceinline__ void gemm_core_128(const bf16* __restrict__ A,
                                              const bf16* __restrict__ W,
                                              int m0, int n0, int tid,
                                              uint4* sA, uint4* sB,
                                              f32x4 acc[4][4]) {
  const int lane = tid & 63, quad = lane >> 4, l16 = lane & 15;
  const int wave = tid >> 6;
  const int wm = (wave >> 1) * 64, wn = (wave & 1) * 64;
#pragma unroll
  for (int i = 0; i < 4; i++)
#pragma unroll
    for (int j = 0; j < 4; j++) {
      f32x4 z = {0.f, 0.f, 0.f, 0.f};
      acc[i][j] = z;
    }
  for (int kk = 0; kk < 16; kk++) {
    const int k0 = kk * 64;
    __syncthreads();
#pragma unroll
    for (int t = 0; t < 4; t++) {
      int c = t * 256 + tid;
      int r = c >> 3, jb = (c & 7) ^ (r & 7);
      g2lds16(A + (size_t)(m0 + r) * 1024 + k0 + jb * 8, sA + c);
    }
#pragma unroll
    for (int t = 0; t < 4; t++) {
      int c = t * 256 + tid;
      int r = c >> 3, jb = (c & 7) ^ (r & 7);
      g2lds16(W + (size_t)(n0 + r) * 1024 + k0 + jb * 8, sB + c);
    }
    __syncthreads();
#pragma unroll
    for (int kc = 0; kc < 2; kc++) {
      bf16x8 af[4], bfr[4];
#pragma unroll
      for (int i = 0; i < 4; i++) {
        int row = wm + i * 16 + l16;
        af[i] = *(const bf16x8*)(sA + row * 8 + (((kc << 2) + quad) ^ (row & 7)));
      }
#pragma unroll
      for (int j = 0; j < 4; j++) {
        int row = wn + j * 16 + l16;
        bfr[j] = *(const bf16x8*)(sB + row * 8 + (((kc << 2) + quad) ^ (row & 7)));
      }
#pragma unroll
      for (int i = 0; i < 4; i++)
#pragma unroll
        for (int j = 0; j < 4; j++)
          acc[i][j] = MFMA16(af[i], bfr[j], acc[i][j]);
    }
  }
}

// C/D layout: row(m) = quad*4 + reg, col(n) = lane&15 (m89/m91 verified).

// QKV projection (bf16 temps in, bf16 internal out; fp32 bias).
__global__ __launch_bounds__(256, 3) void qkv_gemm(
    const bf16* __restrict__ qin, const bf16* __restrict__ kin,
    const bf16* __restrict__ vin, const bf16* __restrict__ Wq,
    const bf16* __restrict__ Wk, const bf16* __restrict__ Wv,
    const float* __restrict__ bq, const float* __restrict__ bk,
    const float* __restrict__ bv, bf16* __restrict__ qw, bf16* __restrict__ kw,
    bf16* __restrict__ vTw) {
  __shared__ uint4 sA[1024], sB[1024];
  const int z = blockIdx.z;
  const bf16* A = (z == 0) ? qin : (z == 1) ? kin : vin;
  const bf16* W = (z == 0) ? Wq : (z == 1) ? Wk : Wv;
  const float* bias = (z == 0) ? bq : (z == 1) ? bk : bv;
  const int m0 = blockIdx.x * 128, n0 = blockIdx.y * 128;
  const int tid = threadIdx.x;
  f32x4 acc[4][4];
  gemm_core_128(A, W, m0, n0, tid, sA, sB, acc);
  const int lane = tid & 63, quad = lane >> 4, l16 = lane & 15;
  const int wave = tid >> 6;
  const int wm = (wave >> 1) * 64, wn = (wave & 1) * 64;
  if (z < 2) {
    bf16* out = (z == 0) ? qw : kw;
#pragma unroll
    for (int j = 0; j < 4; j++) {
      int n = n0 + wn + j * 16 + l16;
      float bvv = bias[n];
      int h = n >> 6, dk = n & 63;
#pragma unroll
      for (int i = 0; i < 4; i++) {
        int mbase = m0 + wm + i * 16 + quad * 4;
#pragma unroll
        for (int r = 0; r < 4; r++) {
          int m = mbase + r;
          int b = m >> 11, s = m & 2047;
          out[(((size_t)(b * 16 + h) * 2048 + s) << 6) + dk] =
              (bf16)(acc[i][j][r] + bvv);
        }
      }
    }
  } else {
#pragma unroll
    for (int j = 0; j < 4; j++) {
      int n = n0 + wn + j * 16 + l16;
      float bvv = bias[n];
      int h = n >> 6, dk = n & 63;
#pragma unroll
      for (int i = 0; i < 4; i++) {
        int m = m0 + wm + i * 16 + quad * 4;
        int b = m >> 11, s = m & 2047;
        union { bf16 hh[4]; uint2 u; } tmp;
#pragma unroll
        for (int r = 0; r < 4; r++) tmp.hh[r] = (bf16)(acc[i][j][r] + bvv);
        *(uint2*)&vTw[((size_t)((b * 16 + h) * 64 + dk) << 11) + s] = tmp.u;
      }
    }
  }
}

// Output projection, BN=64 variant: grid 32x16 = 512 blocks -> 4 blocks/CU
// (was 32x8 = 256 = 1 block/CU, zero TLP). Same m97 template, narrower B.
__global__ __launch_bounds__(256, 4) void out_gemm(const bf16* __restrict__ X,
                                                   const bf16* __restrict__ Wo,
                                                   const float* __restrict__ bo,
                                                   float* __restrict__ out) {
  __shared__ uint4 sA[1024], sB[512];
  const int m0 = blockIdx.x * 128, n0 = blockIdx.y * 64;
  const int tid = threadIdx.x;
  const int lane = tid & 63, quad = lane >> 4, l16 = lane & 15;
  const int wave = tid >> 6;
  const int wm = (wave >> 1) * 64, wn = (wave & 1) * 32;
  f32x4 acc[4][2];
#pragma unroll
  for (int i = 0; i < 4; i++)
#pragma unroll
    for (int j = 0; j < 2; j++) {
      f32x4 z = {0.f, 0.f, 0.f, 0.f};
      acc[i][j] = z;
    }
  for (int kk = 0; kk < 16; kk++) {
    const int k0 = kk * 64;
    __syncthreads();
#pragma unroll
    for (int t = 0; t < 4; t++) {
      int c = t * 256 + tid;
      int r = c >> 3, jb = (c & 7) ^ (r & 7);
      g2lds16(X + (size_t)(m0 + r) * 1024 + k0 + jb * 8, sA + c);
    }
#pragma unroll
    for (int t = 0; t < 2; t++) {
      int c = t * 256 + tid;
      int r = c >> 3, jb = (c & 7) ^ (r & 7);
      g2lds16(Wo + (size_t)(n0 + r) * 1024 + k0 + jb * 8, sB + c);
    }
    __syncthreads();
#pragma unroll
    for (int kc = 0; kc < 2; kc++) {
      bf16x8 af[4], bfr[2];
#pragma unroll
      for (int i = 0; i < 4; i++) {
        int row = wm + i * 16 + l16;
        af[i] = *(const bf16x8*)(sA + row * 8 + (((kc << 2) + quad) ^ (row & 7)));
      }
#pragma unroll
      for (int j = 0; j < 2; j++) {
        int row = wn + j * 16 + l16;
        bfr[j] = *(const bf16x8*)(sB + row * 8 + (((kc << 2) + quad) ^ (row & 7)));
      }
#pragma unroll
      for (int i = 0; i < 4; i++)
#pragma unroll
        for (int j = 0; j < 2; j++)
          acc[i][j] = MFMA16(af[i], bfr[j], acc[i][j]);
    }
  }
#pragma unroll
  for (int j = 0; j < 2; j++) {
    int n = n0 + wn + j * 16 + l16;
    float bvv = bo[n];
#pragma unroll
    for (int i = 0; i < 4; i++) {
      int mbase = m0 + wm + i * 16 + quad * 4;
#pragma unroll
      for (int r = 0; r < 4; r++) {
        int m = mbase + r;
        out[((size_t)m << 10) + n] = acc[i][j][r] + bvv;
      }
    }
  }
}

// ---------------------------------------------------------------------------
// Attention: exact r4 config (local optimum, bracketed by r3/r5/r6):
// QBLK=64, KVBLK=128, LDS 64 KiB, 2 blocks/CU, K dbuf + 1-phase-ahead
// prefetch, fixed-shift softmax, NT fp32 attn stores, XCD swizzle.
// ---------------------------------------------------------------------------
__global__ __launch_bounds__(256, 2) void attn_kernel(
    const bf16* __restrict__ qw, const bf16* __restrict__ kw,
    const bf16* __restrict__ vT, const int* __restrict__ mask,
    float* __restrict__ attnF, bf16* __restrict__ xw) {
  __shared__ uint4 smem[4096];  // 64 KiB: sK dbuf (2x16K) | sV (16K) | sP/sQ (16K)
  uint4* const sK0 = smem;
  uint4* const sK1 = smem + 1024;
  uint4* const sV = smem + 2048;
  uint4* const sP = smem + 3072;
  uint4* const sQ = smem + 3072;  // alias: Q consumed before first sP write

  const int tid = threadIdx.x, wave = tid >> 6, lane = tid & 63;
  const int quad = lane >> 4, l16 = lane & 15;
  // bijective XCD swizzle (nwg=1024 % 8 == 0): XCD k gets bh in [4k, 4k+4)
  const int wgid = blockIdx.y * 32 + blockIdx.x;
  const int swz = (wgid & 7) * 128 + (wgid >> 3);
  const int qt = swz & 31, bh = swz >> 5, b = bh >> 4, h = bh & 15;
  const int q0 = qt * 64;
  const bf16* qbase = qw + (size_t)bh * (2048 * 64);
  const bf16* kbase = kw + (size_t)bh * (2048 * 64);
  const bf16* vbase = vT + (size_t)bh * (64 * 2048);
  const int* mrow = mask + b * 2048;

  const float SC = 0.125f * 1.44269504f;  // log2(e)/8

  auto stageK = [&](uint4* buf, int kt) {
#pragma unroll
    for (int t = 0; t < 4; t++) {
      int c = t * 256 + tid;
      int r = c >> 3, jb = (c & 7) ^ (r & 7);
      g2lds16(kbase + (size_t)(kt * 128 + r) * 64 + jb * 8, buf + c);
    }
  };
  auto stageV = [&](int kt) {
#pragma unroll
    for (int t = 0; t < 4; t++) {
      int c = t * 256 + tid;
      int rv = c >> 4, jb = (c & 15) ^ (rv & 15);
      g2lds16(vbase + (size_t)rv * 2048 + kt * 128 + jb * 8, sV + c);
    }
  };

  // stage Q (8 KiB, into sP region) + K tile 0; one drain for both
#pragma unroll
  for (int t = 0; t < 2; t++) {
    int c = t * 256 + tid;
    int r = c >> 3, jb = (c & 7) ^ (r & 7);
    g2lds16(qbase + (size_t)(q0 + r) * 64 + jb * 8, sQ + c);
  }
  stageK(sK0, 0);
  __syncthreads();

  bf16x8 aq[2];
  {
    int row = wave * 16 + l16;
    aq[0] = *(const bf16x8*)(sQ + row * 8 + ((quad) ^ (row & 7)));
    aq[1] = *(const bf16x8*)(sQ + row * 8 + ((4 + quad) ^ (row & 7)));
  }
  float lpart[4];
#pragma unroll
  for (int r = 0; r < 4; r++) lpart[r] = 0.f;

  // -------- Pass A: per-lane exp2 partial sums; 1 barrier/kt ----------------
  for (int kt = 0; kt < 16; kt++) {
    uint4* kcur = (kt & 1) ? sK1 : sK0;
    if (kt < 15) {
      stageK((kt & 1) ? sK0 : sK1, kt + 1);  // prefetch next K
    } else {
      stageK(sK0, 0);  // pre-stage pass B's first tiles
      stageV(0);
    }
    f32x4 sc[8];
#pragma unroll
    for (int ns = 0; ns < 8; ns++) {
      f32x4 z = {0.f, 0.f, 0.f, 0.f};
      sc[ns] = z;
    }
#pragma unroll
    for (int kc = 0; kc < 2; kc++)
#pragma unroll
      for (int ns = 0; ns < 8; ns++) {
        int row = ns * 16 + l16;
        bf16x8 bk =
            *(const bf16x8*)(kcur + row * 8 + (((kc << 2) + quad) ^ (row & 7)));
        sc[ns] = MFMA16(aq[kc], bk, sc[ns]);
      }
#pragma unroll
    for (int ns = 0; ns < 8; ns++) {
      float madd = (mrow[kt * 128 + ns * 16 + l16] == 0) ? -1.0e9f : 0.0f;
#pragma unroll
      for (int r = 0; r < 4; r++)
        lpart[r] += exp2f(sc[ns][r] * SC + madd);
    }
    __syncthreads();  // protects kcur for overwrite; drains prefetch
  }

  float invl[4];
  size_t arow[4];
#pragma unroll
  for (int r = 0; r < 4; r++) {
    float v = lpart[r];
#pragma unroll
    for (int off = 8; off >= 1; off >>= 1) v += __shfl_xor(v, off, 16);
    invl[r] = 1.f / fmaxf(v, 1.0e-30f);
    arow[r] = (size_t)(bh * 2048 + q0 + wave * 16 + quad * 4 + r) * 2048;
  }
  f32x4 xacc[4];
#pragma unroll
  for (int nd = 0; nd < 4; nd++) {
    f32x4 z = {0.f, 0.f, 0.f, 0.f};
    xacc[nd] = z;
  }
  bf16* sPb = (bf16*)sP;

  // -------- Pass B: recompute scores, store exact attn, PV ------------------
  for (int kt = 0; kt < 16; kt++) {
    uint4* kcur = (kt & 1) ? sK1 : sK0;
    if (kt < 15) stageK((kt & 1) ? sK0 : sK1, kt + 1);  // prefetch next K
    f32x4 sc[8];
#pragma unroll
    for (int ns = 0; ns < 8; ns++) {
      f32x4 z = {0.f, 0.f, 0.f, 0.f};
      sc[ns] = z;
    }
#pragma unroll
    for (int kc = 0; kc < 2; kc++)
#pragma unroll
      for (int ns = 0; ns < 8; ns++) {
        int row = ns * 16 + l16;
        bf16x8 bk =
            *(const bf16x8*)(kcur + row * 8 + (((kc << 2) + quad) ^ (row & 7)));
        sc[ns] = MFMA16(aq[kc], bk, sc[ns]);
      }
#pragma unroll
    for (int ns = 0; ns < 8; ns++) {
      float madd = (mrow[kt * 128 + ns * 16 + l16] == 0) ? -1.0e9f : 0.0f;
      int col = ns * 16 + l16;
#pragma unroll
      for (int r = 0; r < 4; r++) {
        float p = exp2f(sc[ns][r] * SC + madd) * invl[r];
        sc[ns][r] = p;
        int qrow = wave * 16 + quad * 4 + r;
        int chunk = qrow * 16 + ((col >> 3) ^ (qrow & 15));
        sPb[chunk * 8 + (col & 7)] = (bf16)p;
      }
    }
    __syncthreads();  // B1: sP visible; V(kt) + K(kt+1) drained
    // PV: A = own wave's 16 q-rows of P, B = V^T tile
#pragma unroll
    for (int kc2 = 0; kc2 < 4; kc2++) {
      int rowp = wave * 16 + l16;
      bf16x8 ap =
          *(const bf16x8*)(sP + rowp * 16 + (((kc2 << 2) + quad) ^ (rowp & 15)));
#pragma unroll
      for (int nd = 0; nd < 4; nd++) {
        int rv = nd * 16 + l16;
        bf16x8 bv =
            *(const bf16x8*)(sV + rv * 16 + (((kc2 << 2) + quad) ^ (rv & 15)));
        xacc[nd] = MFMA16(ap, bv, xacc[nd]);
      }
    }
    __syncthreads();  // B2: all waves done reading sV/sP
    if (kt < 15) stageV(kt + 1);  // overlaps next QK^T+softmax, drains at B1
    // attn stores from registers; nontemporal (bypass L2), drain at next B1
#pragma unroll
    for (int ns = 0; ns < 8; ns++) {
      int col = kt * 128 + ns * 16 + l16;
#pragma unroll
      for (int r = 0; r < 4; r++)
        __builtin_nontemporal_store(sc[ns][r], &attnF[arow[r] + col]);
    }
  }
#pragma unroll
  for (int nd = 0; nd < 4; nd++) {
    int dk = nd * 16 + l16;
#pragma unroll
    for (int r = 0; r < 4; r++) {
      int qrow = q0 + wave * 16 + quad * 4 + r;
      xw[((size_t)(b * 2048 + qrow) << 10) + h * 64 + dk] = (bf16)xacc[nd][r];
    }
  }
}

extern "C" void kernel_launch(void* const* d_in, const int* in_sizes, int n_in,
                              void* d_out, int out_size, void* d_ws,
                              size_t ws_size, hipStream_t stream) {
  const float* query = (const float*)d_in[0];
  const float* key = (const float*)d_in[1];
  const float* value = (const float*)d_in[2];
  const int* mask = (const int*)d_in[3];
  const float* Wq = (const float*)d_in[4];
  const float* bq = (const float*)d_in[5];
  const float* Wk = (const float*)d_in[6];
  const float* bk = (const float*)d_in[7];
  const float* Wv = (const float*)d_in[8];
  const float* bv = (const float*)d_in[9];
  const float* Wo = (const float*)d_in[10];
  const float* bo = (const float*)d_in[11];

  float* outF = (float*)d_out;           // [4096][1024] fp32
  float* attnF = outF + (size_t)4194304; // [32][2048][2048] fp32

  // bf16 temps carved from the (not-yet-written) attn region of d_out:
  bf16* tQ = (bf16*)attnF;               // 4Mi elems
  bf16* tK = tQ + (size_t)4194304;
  bf16* tV = tK + (size_t)4194304;
  bf16* tWq = tV + (size_t)4194304;      // 1Mi elems each
  bf16* tWk = tWq + (size_t)1048576;
  bf16* tWv = tWk + (size_t)1048576;     // 30 MiB total << 537 MB region

  bf16* qw = (bf16*)d_ws;                // internal bf16 q  8 MiB
  bf16* kw = qw + (size_t)4194304;       // 8 MiB
  bf16* vT = kw + (size_t)4194304;       // 8 MiB
  bf16* xw = vT + (size_t)4194304;       // 8 MiB
  bf16* WoB = xw + (size_t)4194304;      // 2 MiB (must outlive attn_kernel)

  cvt_all<<<dim3(8192), 256, 0, stream>>>(query, key, value, Wq, Wk, Wv, Wo,
                                          tQ, tK, tV, tWq, tWk, tWv, WoB);
  qkv_gemm<<<dim3(32, 8, 3), 256, 0, stream>>>(tQ, tK, tV, tWq, tWk, tWv, bq,
                                               bk, bv, qw, kw, vT);
  attn_kernel<<<dim3(32, 32), 256, 0, stream>>>(qw, kw, vT, mask, attnF, xw);
  out_gemm<<<dim3(32, 16), 256, 0, stream>>>(xw, WoB, bo, outF);
}